// Round 1
// baseline (494.506 us; speedup 1.0000x reference)
//
#include <hip/hip_runtime.h>
#include <hip/hip_bf16.h>
#include <stdint.h>

#define B_ 2
#define Qn 2048
#define Kn 2048
#define Hn 16
#define Dn 128
#define QT 64      // q rows per block (4 waves x 16)
#define KT 32      // keys per K-tile
#define HD (Hn*Dn)

typedef __bf16 bf16x8 __attribute__((ext_vector_type(8)));
typedef float f32x4 __attribute__((ext_vector_type(4)));

union BF8 { ushort u[8]; bf16x8 v; };

__device__ __forceinline__ ushort f2bf(float f) {
  union { float f; uint32_t u; } x; x.f = f;
  uint32_t r = x.u + 0x7FFFu + ((x.u >> 16) & 1u);   // round-to-nearest-even
  return (ushort)(r >> 16);
}

__global__ __launch_bounds__(256) void attn_fwd(
    const float* __restrict__ qs, const float* __restrict__ ks,
    const float* __restrict__ vs, const int* __restrict__ vlen,
    float* __restrict__ ctx_out, float* __restrict__ attn_out)
{
  __shared__ float Ksm[KT][Dn + 4];
  __shared__ float Vsm[KT][Dn + 4];
  __shared__ ushort Psm[4][16][KT + 8];

  const int tid  = threadIdx.x;
  const int wave = tid >> 6;
  const int lane = tid & 63;
  const int c = lane & 15;      // A: q-row / B: key-col / C: col
  const int g = lane >> 4;      // k-group

  const int bh = blockIdx.y;
  const int b  = bh >> 4;       // Hn = 16
  const int h  = bh & 15;
  const int vl = vlen[b];
  const int qb = blockIdx.x * QT + wave * 16;

  // ---- hoisted Q fragments: 4 MFMA K-steps (32 each) over D=128 ----
  // consistent packing: element j of group g holds k = g*8 + j (within a 32-k step)
  BF8 qf[4];
  {
    const float* qrow = qs + (((size_t)(b * Qn + qb + c)) * Hn + h) * Dn;
    #pragma unroll
    for (int s = 0; s < 4; ++s)
      #pragma unroll
      for (int j = 0; j < 8; ++j)
        qf[s].u[j] = f2bf(qrow[s * 32 + g * 8 + j]);
  }

  const float scale = 0.088388347648318447f;  // 1/sqrt(128)

  // ---------------- pass 1: row sums of exp ----------------
  float rs[4] = {0.f, 0.f, 0.f, 0.f};
  const int nkt_v = (vl + KT - 1) / KT;   // tiles containing any valid key
  for (int kt = 0; kt < nkt_v; ++kt) {
    const float* kb_p = ks + ((size_t)(b * Kn + kt * KT) * Hn + h) * Dn;
    #pragma unroll
    for (int i = 0; i < 4; ++i) {
      int f = tid + i * 256;
      int row = f >> 5, cv = f & 31;
      *(f32x4*)&Ksm[row][cv * 4] = *(const f32x4*)(kb_p + (size_t)row * HD + cv * 4);
    }
    __syncthreads();
    #pragma unroll
    for (int nt = 0; nt < 2; ++nt) {
      f32x4 acc = {0.f, 0.f, 0.f, 0.f};
      #pragma unroll
      for (int s = 0; s < 4; ++s) {
        BF8 kf;
        const float* kr = &Ksm[nt * 16 + c][s * 32 + g * 8];
        #pragma unroll
        for (int j = 0; j < 8; ++j) kf.u[j] = f2bf(kr[j]);
        acc = __builtin_amdgcn_mfma_f32_16x16x32_bf16(qf[s].v, kf.v, acc, 0, 0, 0);
      }
      const int kcol = kt * KT + nt * 16 + c;
      #pragma unroll
      for (int r = 0; r < 4; ++r) {
        float p = (kcol < vl) ? __expf(acc[r] * scale) : 0.f;
        rs[r] += p;
      }
    }
    __syncthreads();
  }

  float inv[4];
  #pragma unroll
  for (int r = 0; r < 4; ++r) {
    float v = rs[r];
    v += __shfl_xor(v, 1);
    v += __shfl_xor(v, 2);
    v += __shfl_xor(v, 4);
    v += __shfl_xor(v, 8);
    inv[r] = 1.0f / v;
  }

  // ---------------- pass 2: write attn, accumulate PV ----------------
  f32x4 ctxa[8];
  #pragma unroll
  for (int i = 0; i < 8; ++i) ctxa[i] = (f32x4){0.f, 0.f, 0.f, 0.f};

  for (int kt = 0; kt < Kn / KT; ++kt) {
    if (kt * KT >= vl) {
      // fully masked tile: attention is exactly 0
      #pragma unroll
      for (int nt = 0; nt < 2; ++nt)
        #pragma unroll
        for (int r = 0; r < 4; ++r)
          attn_out[((size_t)bh * Qn + qb + g * 4 + r) * Kn + kt * KT + nt * 16 + c] = 0.f;
      continue;  // block-uniform branch (vl uniform per block)
    }
    const float* kb_p = ks + ((size_t)(b * Kn + kt * KT) * Hn + h) * Dn;
    const float* vb_p = vs + ((size_t)(b * Kn + kt * KT) * Hn + h) * Dn;
    #pragma unroll
    for (int i = 0; i < 4; ++i) {
      int f = tid + i * 256;
      int row = f >> 5, cv = f & 31;
      *(f32x4*)&Ksm[row][cv * 4] = *(const f32x4*)(kb_p + (size_t)row * HD + cv * 4);
      *(f32x4*)&Vsm[row][cv * 4] = *(const f32x4*)(vb_p + (size_t)row * HD + cv * 4);
    }
    __syncthreads();

    #pragma unroll
    for (int nt = 0; nt < 2; ++nt) {
      f32x4 acc = {0.f, 0.f, 0.f, 0.f};
      #pragma unroll
      for (int s = 0; s < 4; ++s) {
        BF8 kf;
        const float* kr = &Ksm[nt * 16 + c][s * 32 + g * 8];
        #pragma unroll
        for (int j = 0; j < 8; ++j) kf.u[j] = f2bf(kr[j]);
        acc = __builtin_amdgcn_mfma_f32_16x16x32_bf16(qf[s].v, kf.v, acc, 0, 0, 0);
      }
      const int kcol = kt * KT + nt * 16 + c;
      #pragma unroll
      for (int r = 0; r < 4; ++r) {
        float p = (kcol < vl) ? __expf(acc[r] * scale) * inv[r] : 0.f;
        attn_out[((size_t)bh * Qn + qb + g * 4 + r) * Kn + kcol] = p;
        Psm[wave][g * 4 + r][nt * 16 + c] = f2bf(p);
      }
    }
    __syncthreads();   // Psm visibility across lanes (conservative)

    // PV: A = P (16q x 32k), B = V (32k x 16d per n-tile), same k-packing as A
    BF8 pf;
    #pragma unroll
    for (int j = 0; j < 8; ++j) pf.u[j] = Psm[wave][c][g * 8 + j];
    #pragma unroll
    for (int n8 = 0; n8 < 8; ++n8) {
      BF8 vf;
      #pragma unroll
      for (int j = 0; j < 8; ++j) vf.u[j] = f2bf(Vsm[g * 8 + j][n8 * 16 + c]);
      ctxa[n8] = __builtin_amdgcn_mfma_f32_16x16x32_bf16(pf.v, vf.v, ctxa[n8], 0, 0, 0);
    }
    __syncthreads();   // before next tile overwrites Ksm/Vsm
  }

  // ---------------- epilogue: ctx (B,Q,H,D) ----------------
  #pragma unroll
  for (int n8 = 0; n8 < 8; ++n8)
    #pragma unroll
    for (int r = 0; r < 4; ++r)
      ctx_out[((size_t)(b * Qn + qb + g * 4 + r) * Hn + h) * Dn + n8 * 16 + c] = ctxa[n8][r];
}

extern "C" void kernel_launch(void* const* d_in, const int* in_sizes, int n_in,
                              void* d_out, int out_size, void* d_ws, size_t ws_size,
                              hipStream_t stream) {
  const float* qs   = (const float*)d_in[0];
  const float* ks   = (const float*)d_in[1];
  const float* vs   = (const float*)d_in[2];
  const int*   vlen = (const int*)d_in[3];
  float* ctx  = (float*)d_out;
  float* attn = ctx + (size_t)B_ * Qn * Hn * Dn;   // outputs concatenated: ctx, attn
  dim3 grid(Qn / QT, B_ * Hn);
  attn_fwd<<<grid, 256, 0, stream>>>(qs, ks, vs, vlen, ctx, attn);
}

// Round 2
// 250.981 us; speedup vs baseline: 1.9703x; 1.9703x over previous
//
#include <hip/hip_runtime.h>
#include <hip/hip_bf16.h>
#include <stdint.h>

#define B_ 2
#define Qn 2048
#define Kn 2048
#define Hn 16
#define Dn 128
#define QT 64      // q rows per block (4 waves x 16)
#define KT 32      // keys per K-tile
#define HD (Hn*Dn)

typedef __bf16 bf16x8 __attribute__((ext_vector_type(8)));
typedef float f32x4 __attribute__((ext_vector_type(4)));
typedef unsigned short u16x4_t __attribute__((ext_vector_type(4)));

union BF8 { unsigned short u[8]; bf16x8 v; };
union BF4 { unsigned short u[4]; u16x4_t v; };

__device__ __forceinline__ unsigned short f2bf(float f) {
  union { float f; uint32_t u; } x; x.f = f;
  uint32_t r = x.u + 0x7FFFu + ((x.u >> 16) & 1u);   // round-to-nearest-even
  return (unsigned short)(r >> 16);
}

__global__ __launch_bounds__(256) void attn_fwd(
    const float* __restrict__ qs, const float* __restrict__ ks,
    const float* __restrict__ vs, const int* __restrict__ vlen,
    float* __restrict__ ctx_out, float* __restrict__ attn_out)
{
  // bf16 LDS tiles, fragment-friendly layouts
  __shared__ __align__(16) unsigned short Ksm[KT][Dn + 8];   // 272B stride: b128 reads conflict-free
  __shared__ __align__(16) unsigned short Vt[Dn][KT];        // transposed V, XOR quad-swizzled
  __shared__ __align__(16) unsigned short Psm[4][16][40];    // per-wave P, 80B stride

  const int tid  = threadIdx.x;
  const int wave = tid >> 6;
  const int lane = tid & 63;
  const int c = lane & 15;      // A: q-row / B: key-col or d-col / C: col
  const int g = lane >> 4;      // k-group (elements g*8..g*8+7)

  const int bh = blockIdx.y;
  const int b  = bh >> 4;       // Hn = 16
  const int h  = bh & 15;
  const int vl = vlen[b];
  const int qb = blockIdx.x * QT + wave * 16;

  // ---- hoisted Q fragments (4 K-steps of 32 over D=128), vectorized loads ----
  BF8 qf[4];
  {
    const float* qrow = qs + (((size_t)(b * Qn + qb + c)) * Hn + h) * Dn;
    #pragma unroll
    for (int s = 0; s < 4; ++s) {
      f32x4 a0 = *(const f32x4*)(qrow + s * 32 + g * 8);
      f32x4 a1 = *(const f32x4*)(qrow + s * 32 + g * 8 + 4);
      #pragma unroll
      for (int j = 0; j < 4; ++j) { qf[s].u[j] = f2bf(a0[j]); qf[s].u[4 + j] = f2bf(a1[j]); }
    }
  }

  const float scale = 0.088388347648318447f;  // 1/sqrt(128)
  const int nkt_v = (vl + KT - 1) / KT;
  const char* vtbase = (const char*)&Vt[0][0];
  const int vswz = ((c >> 1) & 3) << 4;   // read-side quad swizzle for Vt

  // ---------------- pass 1: row sums of exp ----------------
  float rs[4] = {0.f, 0.f, 0.f, 0.f};
  for (int kt = 0; kt < nkt_v; ++kt) {
    const float* kb_p = ks + ((size_t)(b * Kn + kt * KT) * Hn + h) * Dn;
    #pragma unroll
    for (int i = 0; i < 4; ++i) {
      int chunk = i * 256 + tid;
      int row = chunk >> 5, cv = chunk & 31;
      f32x4 a = *(const f32x4*)(kb_p + (size_t)row * HD + cv * 4);
      BF4 t;
      #pragma unroll
      for (int j = 0; j < 4; ++j) t.u[j] = f2bf(a[j]);
      *(u16x4_t*)&Ksm[row][cv * 4] = t.v;
    }
    __syncthreads();
    #pragma unroll
    for (int nt = 0; nt < 2; ++nt) {
      f32x4 acc = {0.f, 0.f, 0.f, 0.f};
      #pragma unroll
      for (int s = 0; s < 4; ++s) {
        BF8 kf; kf.v = *(const bf16x8*)&Ksm[nt * 16 + c][s * 32 + g * 8];
        acc = __builtin_amdgcn_mfma_f32_16x16x32_bf16(qf[s].v, kf.v, acc, 0, 0, 0);
      }
      const int kcol = kt * KT + nt * 16 + c;
      #pragma unroll
      for (int r = 0; r < 4; ++r)
        rs[r] += (kcol < vl) ? __expf(acc[r] * scale) : 0.f;
    }
    __syncthreads();
  }

  float inv[4];
  #pragma unroll
  for (int r = 0; r < 4; ++r) {
    float v = rs[r];
    v += __shfl_xor(v, 1);
    v += __shfl_xor(v, 2);
    v += __shfl_xor(v, 4);
    v += __shfl_xor(v, 8);
    inv[r] = 1.0f / v;
  }

  // ---------------- pass 2: write attn, accumulate PV ----------------
  f32x4 ctxa[8];
  #pragma unroll
  for (int i = 0; i < 8; ++i) ctxa[i] = (f32x4){0.f, 0.f, 0.f, 0.f};

  const int dstage = tid & 127;              // d-column this thread stages for Vt
  const int vwswz  = ((dstage >> 1) & 3) << 4;

  for (int kt = 0; kt < nkt_v; ++kt) {
    const float* kb_p = ks + ((size_t)(b * Kn + kt * KT) * Hn + h) * Dn;
    const float* vb_p = vs + ((size_t)(b * Kn + kt * KT) * Hn + h) * Dn;
    // stage K (row-major bf16, padded)
    #pragma unroll
    for (int i = 0; i < 4; ++i) {
      int chunk = i * 256 + tid;
      int row = chunk >> 5, cv = chunk & 31;
      f32x4 a = *(const f32x4*)(kb_p + (size_t)row * HD + cv * 4);
      BF4 t;
      #pragma unroll
      for (int j = 0; j < 4; ++j) t.u[j] = f2bf(a[j]);
      *(u16x4_t*)&Ksm[row][cv * 4] = t.v;
    }
    // stage V transposed (each thread packs one d-column of 8 k's -> one b128)
    #pragma unroll
    for (int rr = 0; rr < 2; ++rr) {
      int kb2 = rr * 2 + (tid >> 7);         // 16B quad index (8 keys)
      const float* colp = vb_p + (size_t)(kb2 * 8) * HD + dstage;
      BF8 t;
      #pragma unroll
      for (int j = 0; j < 8; ++j) t.u[j] = f2bf(colp[(size_t)j * HD]);
      int byteoff = dstage * 64 + ((kb2 * 16) ^ vwswz);
      *(bf16x8*)((char*)&Vt[0][0] + byteoff) = t.v;
    }
    __syncthreads();

    // QK^T -> P (normalized), write attn, stash P in wave-private LDS
    #pragma unroll
    for (int nt = 0; nt < 2; ++nt) {
      f32x4 acc = {0.f, 0.f, 0.f, 0.f};
      #pragma unroll
      for (int s = 0; s < 4; ++s) {
        BF8 kf; kf.v = *(const bf16x8*)&Ksm[nt * 16 + c][s * 32 + g * 8];
        acc = __builtin_amdgcn_mfma_f32_16x16x32_bf16(qf[s].v, kf.v, acc, 0, 0, 0);
      }
      const int kcol = kt * KT + nt * 16 + c;
      #pragma unroll
      for (int r = 0; r < 4; ++r) {
        float p = (kcol < vl) ? __expf(acc[r] * scale) * inv[r] : 0.f;
        attn_out[((size_t)bh * Qn + qb + g * 4 + r) * Kn + kcol] = p;
        Psm[wave][g * 4 + r][nt * 16 + c] = f2bf(p);
      }
    }
    // wave-private LDS: order writes before reads without a block barrier
    asm volatile("s_waitcnt lgkmcnt(0)" ::: "memory");
    __builtin_amdgcn_sched_barrier(0);

    BF8 pf; pf.v = *(const bf16x8*)&Psm[wave][c][g * 8];
    #pragma unroll
    for (int n8 = 0; n8 < 8; ++n8) {
      BF8 vf;
      vf.v = *(const bf16x8*)(vtbase + (n8 * 16 + c) * 64 + ((g * 16) ^ vswz));
      ctxa[n8] = __builtin_amdgcn_mfma_f32_16x16x32_bf16(pf.v, vf.v, ctxa[n8], 0, 0, 0);
    }
    __syncthreads();   // before next tile's staging overwrites Ksm/Vt
  }

  // ---------------- vectorized zero-fill of fully-masked attn columns ----------------
  const int col0 = nkt_v * KT;   // multiple of 32; cols >= col0 are exactly 0
  #pragma unroll 1
  for (int r = 0; r < 16; ++r) {
    float* rowp = attn_out + ((size_t)bh * Qn + qb + r) * Kn;
    for (int c4 = col0 + lane * 4; c4 < Kn; c4 += 256)
      *(f32x4*)(rowp + c4) = (f32x4){0.f, 0.f, 0.f, 0.f};
  }

  // ---------------- epilogue: ctx (B,Q,H,D) ----------------
  #pragma unroll
  for (int n8 = 0; n8 < 8; ++n8)
    #pragma unroll
    for (int r = 0; r < 4; ++r)
      ctx_out[((size_t)(b * Qn + qb + g * 4 + r) * Hn + h) * Dn + n8 * 16 + c] = ctxa[n8][r];
}

extern "C" void kernel_launch(void* const* d_in, const int* in_sizes, int n_in,
                              void* d_out, int out_size, void* d_ws, size_t ws_size,
                              hipStream_t stream) {
  const float* qs   = (const float*)d_in[0];
  const float* ks   = (const float*)d_in[1];
  const float* vs   = (const float*)d_in[2];
  const int*   vlen = (const int*)d_in[3];
  float* ctx  = (float*)d_out;
  float* attn = ctx + (size_t)B_ * Qn * Hn * Dn;   // outputs concatenated: ctx, attn
  dim3 grid(Qn / QT, B_ * Hn);
  attn_fwd<<<grid, 256, 0, stream>>>(qs, ks, vs, vlen, ctx, attn);
}

// Round 3
// 250.174 us; speedup vs baseline: 1.9766x; 1.0032x over previous
//
#include <hip/hip_runtime.h>
#include <hip/hip_bf16.h>
#include <stdint.h>

#define B_ 2
#define Qn 2048
#define Kn 2048
#define Hn 16
#define Dn 128
#define QT 64      // q rows per block (4 waves x 16)
#define KT 32      // keys per K-tile
#define HD (Hn*Dn)
#define KROW 136   // Ksm row stride in shorts (272 B)
#define VROW 36    // Vt  row stride in shorts (72 B)

typedef __bf16 bf16x8 __attribute__((ext_vector_type(8)));
typedef float f32x4 __attribute__((ext_vector_type(4)));
typedef unsigned short u16x4_t __attribute__((ext_vector_type(4)));

union BF8 { unsigned short u[8]; bf16x8 v; };
union BF4 { unsigned short u[4]; u16x4_t v; };

__device__ __forceinline__ unsigned short f2bf(float f) {
  union { float f; uint32_t u; } x; x.f = f;
  uint32_t r = x.u + 0x7FFFu + ((x.u >> 16) & 1u);   // round-to-nearest-even
  return (unsigned short)(r >> 16);
}

__global__ __launch_bounds__(256, 4) void attn_fwd(
    const float* __restrict__ qs, const float* __restrict__ ks,
    const float* __restrict__ vs, const int* __restrict__ vlen,
    float* __restrict__ ctx_out, float* __restrict__ attn_out)
{
  // double-buffered bf16 tiles
  __shared__ __align__(16) unsigned short Ksm[2][KT][KROW];  // row-major K
  __shared__ __align__(16) unsigned short Vt [2][Dn][VROW];  // V^T, pair-ordered chunks

  const int tid  = threadIdx.x;
  const int wave = tid >> 6;
  const int lane = tid & 63;
  const int c = lane & 15;      // fragment index: q-row (B,N) / dout (A,M of PV)
  const int g = lane >> 4;      // k-group

  const int bh = blockIdx.y;
  const int b  = bh >> 4;       // Hn = 16
  const int h  = bh & 15;
  const int vl = vlen[b];
  const int qb = blockIdx.x * QT + wave * 16;

  // ---- hoisted Q fragments: element j of group g holds d = s*32 + g*8 + j ----
  BF8 qf[4];
  {
    const float* qrow = qs + (((size_t)(b * Qn + qb + c)) * Hn + h) * Dn;
    #pragma unroll
    for (int s = 0; s < 4; ++s) {
      f32x4 a0 = *(const f32x4*)(qrow + s * 32 + g * 8);
      f32x4 a1 = *(const f32x4*)(qrow + s * 32 + g * 8 + 4);
      #pragma unroll
      for (int j = 0; j < 4; ++j) { qf[s].u[j] = f2bf(a0[j]); qf[s].u[4 + j] = f2bf(a1[j]); }
    }
  }

  const float scale = 0.088388347648318447f;  // 1/sqrt(128)
  const int nkt_v = (vl + KT - 1) / KT;
  const float* kbase = ks + ((size_t)b * Kn * Hn + h) * Dn;
  const float* vbase = vs + ((size_t)b * Kn * Hn + h) * Dn;

  #define STAGE_K(kt, bufi) do { \
    const float* kb_p = kbase + (size_t)(kt) * KT * HD; \
    _Pragma("unroll") \
    for (int i = 0; i < 4; ++i) { \
      int chunk = i * 256 + tid; \
      int row = chunk >> 5, cv = chunk & 31; \
      f32x4 a = *(const f32x4*)(kb_p + (size_t)row * HD + cv * 4); \
      BF4 t; \
      _Pragma("unroll") \
      for (int j = 0; j < 4; ++j) t.u[j] = f2bf(a[j]); \
      *(u16x4_t*)&Ksm[bufi][row][cv * 4] = t.v; \
    } } while (0)

  // V^T staging: chunk gg of row d holds keys {4gg..4gg+3, 16+4gg..16+4gg+3}
  #define STAGE_V(kt, bufi) do { \
    const float* vb_p = vbase + (size_t)(kt) * KT * HD; \
    int d = tid & 127; \
    _Pragma("unroll") \
    for (int rr = 0; rr < 2; ++rr) { \
      int gg = (tid >> 7) + 2 * rr; \
      const float* colp = vb_p + d; \
      BF8 t; \
      _Pragma("unroll") \
      for (int j = 0; j < 4; ++j) t.u[j]     = f2bf(colp[(size_t)(4 * gg + j) * HD]); \
      _Pragma("unroll") \
      for (int j = 0; j < 4; ++j) t.u[4 + j] = f2bf(colp[(size_t)(16 + 4 * gg + j) * HD]); \
      *(bf16x8*)&Vt[bufi][d][gg * 8] = t.v; \
    } } while (0)

  // ---------------- pass 1: row sums of exp (swapped QK^T) ----------------
  float rs = 0.f;
  STAGE_K(0, 0);
  __syncthreads();
  for (int kt = 0; kt < nkt_v; ++kt) {
    const int cur = kt & 1;
    if (kt + 1 < nkt_v) STAGE_K(kt + 1, cur ^ 1);
    #pragma unroll
    for (int nt = 0; nt < 2; ++nt) {
      f32x4 acc = {0.f, 0.f, 0.f, 0.f};
      #pragma unroll
      for (int s = 0; s < 4; ++s) {
        BF8 kf; kf.v = *(const bf16x8*)&Ksm[cur][nt * 16 + c][s * 32 + g * 8];
        acc = __builtin_amdgcn_mfma_f32_16x16x32_bf16(kf.v, qf[s].v, acc, 0, 0, 0);
      }
      const int k0 = kt * KT + nt * 16 + g * 4;
      #pragma unroll
      for (int r = 0; r < 4; ++r)
        rs += (k0 + r < vl) ? __expf(acc[r] * scale) : 0.f;
    }
    __syncthreads();
  }
  rs += __shfl_xor(rs, 16);
  rs += __shfl_xor(rs, 32);
  const float inv = 1.0f / rs;   // for q-row (qb + c)

  // ---------------- pass 2: attn (vector stores) + PV from register P ----------------
  f32x4 ctxa[8];
  #pragma unroll
  for (int i = 0; i < 8; ++i) ctxa[i] = (f32x4){0.f, 0.f, 0.f, 0.f};

  STAGE_K(0, 0);
  STAGE_V(0, 0);
  __syncthreads();
  float* rowp = attn_out + ((size_t)bh * Qn + qb + c) * Kn;
  for (int kt = 0; kt < nkt_v; ++kt) {
    const int cur = kt & 1;
    if (kt + 1 < nkt_v) { STAGE_K(kt + 1, cur ^ 1); STAGE_V(kt + 1, cur ^ 1); }

    // S^T: lane (c,g) holds S[q=c][k = kt*32 + nt*16 + g*4 + r]
    BF8 pf;
    #pragma unroll
    for (int nt = 0; nt < 2; ++nt) {
      f32x4 acc = {0.f, 0.f, 0.f, 0.f};
      #pragma unroll
      for (int s = 0; s < 4; ++s) {
        BF8 kf; kf.v = *(const bf16x8*)&Ksm[cur][nt * 16 + c][s * 32 + g * 8];
        acc = __builtin_amdgcn_mfma_f32_16x16x32_bf16(kf.v, qf[s].v, acc, 0, 0, 0);
      }
      const int k0 = kt * KT + nt * 16 + g * 4;
      f32x4 p;
      #pragma unroll
      for (int r = 0; r < 4; ++r) {
        p[r] = (k0 + r < vl) ? __expf(acc[r] * scale) * inv : 0.f;
        pf.u[nt * 4 + r] = f2bf(p[r]);
      }
      *(f32x4*)(rowp + kt * KT + nt * 16 + g * 4) = p;   // 16B vector attn store
    }

    // PV (swapped): ctx^T = V^T * P^T, shared k-permutation {4g+j, 16+4g+j}
    #pragma unroll
    for (int n8 = 0; n8 < 8; ++n8) {
      BF8 vf; vf.v = *(const bf16x8*)&Vt[cur][n8 * 16 + c][g * 8];
      ctxa[n8] = __builtin_amdgcn_mfma_f32_16x16x32_bf16(vf.v, pf.v, ctxa[n8], 0, 0, 0);
    }
    __syncthreads();
  }

  // ---------------- vectorized zero-fill of fully-masked attn columns ----------------
  const int col0 = nkt_v * KT;   // cols >= col0 are exactly 0
  #pragma unroll 1
  for (int r = 0; r < 16; ++r) {
    float* zp = attn_out + ((size_t)bh * Qn + qb + r) * Kn;
    for (int c4 = col0 + lane * 4; c4 < Kn; c4 += 256)
      *(f32x4*)(zp + c4) = (f32x4){0.f, 0.f, 0.f, 0.f};
  }

  // ---------------- epilogue: ctx[q=c][d = n8*16 + g*4 + r], f32x4 stores ----------------
  float* cp = ctx_out + ((size_t)(b * Qn + qb + c) * Hn + h) * Dn;
  #pragma unroll
  for (int n8 = 0; n8 < 8; ++n8)
    *(f32x4*)(cp + n8 * 16 + g * 4) = ctxa[n8];
}

extern "C" void kernel_launch(void* const* d_in, const int* in_sizes, int n_in,
                              void* d_out, int out_size, void* d_ws, size_t ws_size,
                              hipStream_t stream) {
  const float* qs   = (const float*)d_in[0];
  const float* ks   = (const float*)d_in[1];
  const float* vs   = (const float*)d_in[2];
  const int*   vlen = (const int*)d_in[3];
  float* ctx  = (float*)d_out;
  float* attn = ctx + (size_t)B_ * Qn * Hn * Dn;   // outputs concatenated: ctx, attn
  dim3 grid(Qn / QT, B_ * Hn);
  attn_fwd<<<grid, 256, 0, stream>>>(qs, ks, vs, vlen, ctx, attn);
}

// Round 4
// 242.686 us; speedup vs baseline: 2.0376x; 1.0309x over previous
//
#include <hip/hip_runtime.h>
#include <hip/hip_bf16.h>
#include <stdint.h>

#define B_ 2
#define Qn 2048
#define Kn 2048
#define Hn 16
#define Dn 128
#define QT 128     // q rows per block (8 waves x 16)
#define KT 32      // keys per K-tile
#define HD (Hn*Dn)
#define KROW 136   // Ksm row stride in shorts (272 B)
#define VROW 40    // Vt  row stride in shorts (80 B)

typedef __bf16 bf16x8 __attribute__((ext_vector_type(8)));
typedef float f32x4 __attribute__((ext_vector_type(4)));
typedef unsigned short u16x4_t __attribute__((ext_vector_type(4)));

union BF8 { unsigned short u[8]; bf16x8 v; };
union BF4 { unsigned short u[4]; u16x4_t v; };

__device__ __forceinline__ unsigned short f2bf(float f) {
  union { float f; uint32_t u; } x; x.f = f;
  uint32_t r = x.u + 0x7FFFu + ((x.u >> 16) & 1u);   // round-to-nearest-even
  return (unsigned short)(r >> 16);
}

__global__ __launch_bounds__(512, 4) void attn_fwd(
    const float* __restrict__ qs, const float* __restrict__ ks,
    const float* __restrict__ vs, const int* __restrict__ vlen,
    float* __restrict__ ctx_out, float* __restrict__ attn_out)
{
  // double-buffered bf16 tiles (shared by all 8 waves)
  __shared__ __align__(16) unsigned short Ksm[2][KT][KROW];  // row-major K
  __shared__ __align__(16) unsigned short Vt [2][Dn][VROW];  // V^T, pair-ordered chunks

  const int tid  = threadIdx.x;
  const int wave = tid >> 6;
  const int lane = tid & 63;
  const int c = lane & 15;      // fragment index: q-row (B of QK^T) / dout (A of PV)
  const int g = lane >> 4;      // k-group

  // XCD-aware decode: xcd = L&7 pins the bh-group to one XCD; all 16 q-tiles
  // of a bh are co-resident on that XCD -> K/V tile re-reads hit local L2.
  const int L   = blockIdx.x;
  const int xcd = L & 7;
  const int i5  = L >> 3;                 // 0..63
  const int bh  = ((i5 & 3) << 3) + xcd;  // 4 bh per XCD, batches mixed
  const int qt  = i5 >> 2;                // 0..15
  const int b   = bh >> 4;                // Hn = 16
  const int h   = bh & 15;
  const int vl  = vlen[b];
  const int qb  = qt * QT + wave * 16;

  // ---- hoisted Q fragments: element j of group g holds d = s*32 + g*8 + j ----
  BF8 qf[4];
  {
    const float* qrow = qs + (((size_t)(b * Qn + qb + c)) * Hn + h) * Dn;
    #pragma unroll
    for (int s = 0; s < 4; ++s) {
      f32x4 a0 = *(const f32x4*)(qrow + s * 32 + g * 8);
      f32x4 a1 = *(const f32x4*)(qrow + s * 32 + g * 8 + 4);
      #pragma unroll
      for (int j = 0; j < 4; ++j) { qf[s].u[j] = f2bf(a0[j]); qf[s].u[4 + j] = f2bf(a1[j]); }
    }
  }

  const float scale = 0.088388347648318447f;  // 1/sqrt(128)
  const int nkt_v = (vl + KT - 1) / KT;
  const float* kbase = ks + ((size_t)b * Kn * Hn + h) * Dn;
  const float* vbase = vs + ((size_t)b * Kn * Hn + h) * Dn;

  // K tile: 32 rows x 32 f32x4-chunks = 1024 chunks, 512 threads -> 2 each
  #define STAGE_K(kt, bufi) do { \
    const float* kb_p = kbase + (size_t)(kt) * KT * HD; \
    _Pragma("unroll") \
    for (int ii = 0; ii < 2; ++ii) { \
      int chunk = ii * 512 + tid; \
      int row = chunk >> 5, cv = chunk & 31; \
      f32x4 a = *(const f32x4*)(kb_p + (size_t)row * HD + cv * 4); \
      BF4 t; \
      _Pragma("unroll") \
      for (int j = 0; j < 4; ++j) t.u[j] = f2bf(a[j]); \
      *(u16x4_t*)&Ksm[bufi][row][cv * 4] = t.v; \
    } } while (0)

  // V^T staging: chunk gg of row d holds keys {4gg..4gg+3, 16+4gg..16+4gg+3}
  // 128 d x 4 gg = 512 chunks, one per thread
  #define STAGE_V(kt, bufi) do { \
    const float* vb_p = vbase + (size_t)(kt) * KT * HD; \
    int d = tid & 127; \
    int gg = tid >> 7; \
    const float* colp = vb_p + d; \
    BF8 t; \
    _Pragma("unroll") \
    for (int j = 0; j < 4; ++j) t.u[j]     = f2bf(colp[(size_t)(4 * gg + j) * HD]); \
    _Pragma("unroll") \
    for (int j = 0; j < 4; ++j) t.u[4 + j] = f2bf(colp[(size_t)(16 + 4 * gg + j) * HD]); \
    *(bf16x8*)&Vt[bufi][d][gg * 8] = t.v; \
  } while (0)

  // ---------------- pass 1: row sums of exp (swapped QK^T -> S^T) ----------------
  float rs = 0.f;
  STAGE_K(0, 0);
  __syncthreads();
  for (int kt = 0; kt < nkt_v; ++kt) {
    const int cur = kt & 1;
    if (kt + 1 < nkt_v) STAGE_K(kt + 1, cur ^ 1);
    #pragma unroll
    for (int nt = 0; nt < 2; ++nt) {
      f32x4 acc = {0.f, 0.f, 0.f, 0.f};
      #pragma unroll
      for (int s = 0; s < 4; ++s) {
        BF8 kf; kf.v = *(const bf16x8*)&Ksm[cur][nt * 16 + c][s * 32 + g * 8];
        acc = __builtin_amdgcn_mfma_f32_16x16x32_bf16(kf.v, qf[s].v, acc, 0, 0, 0);
      }
      const int k0 = kt * KT + nt * 16 + g * 4;
      #pragma unroll
      for (int r = 0; r < 4; ++r)
        rs += (k0 + r < vl) ? __expf(acc[r] * scale) : 0.f;
    }
    __syncthreads();
  }
  rs += __shfl_xor(rs, 16);
  rs += __shfl_xor(rs, 32);
  const float inv = 1.0f / rs;   // row sum for q-row (qb + c)

  // ---------------- pass 2: attn (vector stores) + PV from register P ----------------
  f32x4 ctxa[8];
  #pragma unroll
  for (int ii = 0; ii < 8; ++ii) ctxa[ii] = (f32x4){0.f, 0.f, 0.f, 0.f};

  STAGE_K(0, 0);
  STAGE_V(0, 0);
  __syncthreads();
  float* rowp = attn_out + ((size_t)bh * Qn + qb + c) * Kn;
  for (int kt = 0; kt < nkt_v; ++kt) {
    const int cur = kt & 1;
    if (kt + 1 < nkt_v) { STAGE_K(kt + 1, cur ^ 1); STAGE_V(kt + 1, cur ^ 1); }

    // S^T: lane (c,g) holds S[q=c][k = kt*32 + nt*16 + g*4 + r]
    BF8 pf;
    #pragma unroll
    for (int nt = 0; nt < 2; ++nt) {
      f32x4 acc = {0.f, 0.f, 0.f, 0.f};
      #pragma unroll
      for (int s = 0; s < 4; ++s) {
        BF8 kf; kf.v = *(const bf16x8*)&Ksm[cur][nt * 16 + c][s * 32 + g * 8];
        acc = __builtin_amdgcn_mfma_f32_16x16x32_bf16(kf.v, qf[s].v, acc, 0, 0, 0);
      }
      const int k0 = kt * KT + nt * 16 + g * 4;
      f32x4 p;
      #pragma unroll
      for (int r = 0; r < 4; ++r) {
        p[r] = (k0 + r < vl) ? __expf(acc[r] * scale) * inv : 0.f;
        pf.u[nt * 4 + r] = f2bf(p[r]);
      }
      *(f32x4*)(rowp + kt * KT + nt * 16 + g * 4) = p;   // 16B vector attn store
    }

    // PV (swapped): ctx^T = V^T * P^T, shared k-permutation {4g+j, 16+4g+j}
    #pragma unroll
    for (int n8 = 0; n8 < 8; ++n8) {
      BF8 vf; vf.v = *(const bf16x8*)&Vt[cur][n8 * 16 + c][g * 8];
      ctxa[n8] = __builtin_amdgcn_mfma_f32_16x16x32_bf16(vf.v, pf.v, ctxa[n8], 0, 0, 0);
    }
    __syncthreads();
  }

  // ---------------- vectorized zero-fill of fully-masked attn columns ----------------
  const int col0 = nkt_v * KT;   // cols >= col0 are exactly 0
  #pragma unroll 1
  for (int r = 0; r < 16; ++r) {
    float* zp = attn_out + ((size_t)bh * Qn + qb + r) * Kn;
    for (int c4 = col0 + lane * 4; c4 < Kn; c4 += 256)
      *(f32x4*)(zp + c4) = (f32x4){0.f, 0.f, 0.f, 0.f};
  }

  // ---------------- epilogue: ctx[q=c][d = n8*16 + g*4 + r], f32x4 stores ----------------
  float* cp = ctx_out + ((size_t)(b * Qn + qb + c) * Hn + h) * Dn;
  #pragma unroll
  for (int n8 = 0; n8 < 8; ++n8)
    *(f32x4*)(cp + n8 * 16 + g * 4) = ctxa[n8];
}

extern "C" void kernel_launch(void* const* d_in, const int* in_sizes, int n_in,
                              void* d_out, int out_size, void* d_ws, size_t ws_size,
                              hipStream_t stream) {
  const float* qs   = (const float*)d_in[0];
  const float* ks   = (const float*)d_in[1];
  const float* vs   = (const float*)d_in[2];
  const int*   vlen = (const int*)d_in[3];
  float* ctx  = (float*)d_out;
  float* attn = ctx + (size_t)B_ * Qn * Hn * Dn;   // outputs concatenated: ctx, attn
  attn_fwd<<<dim3((Qn / QT) * B_ * Hn), 512, 0, stream>>>(qs, ks, vs, vlen, ctx, attn);
}